// Round 5
// baseline (46.202 us; speedup 1.0000x reference)
//
#include <hip/hip_runtime.h>
#include <cmath>

// Masked decode-GEMV: y[n] = sum_z m_z * x_z * W_t[z,n],
// m_z = (|x_z| * ||W_t[z,:]||_2 >= thresh).
//
// Single-read fused design, v2 (direct-to-register pipeline):
//   F: per block, 28 rows; 4-deep NAMED-register row pipeline (no LDS
//      round-trip), deferred-FMA software pipeline, ONE raw s_barrier per
//      row (only for the 4-value cross-wave norm combine). Counted vmcnt
//      is left to the compiler (raw barrier does not drain it).
//   C: reduce 512 partial vectors -> y.
// W is read from HBM exactly once (235 MB); no atomics anywhere.

#define ZDIM   14336
#define NDIM   4096
#define NF4    1024       // float4 per row
#define ZCHUNK 28         // rows per block
#define NBLK   512        // ZDIM / ZCHUNK -> exactly 2 blocks per CU

__global__ __launch_bounds__(256, 2) void fused_norm_gemv(
    const float* __restrict__ x,
    const float* __restrict__ Wt,
    const float* __restrict__ thresh,
    float* __restrict__ part) {
  const int t    = threadIdx.x;
  const int lane = t & 63;
  const int wv   = t >> 6;
  const int z0   = blockIdx.x * ZCHUNK;

  __shared__ float xs[ZCHUNK];
  __shared__ float red[2][4];   // parity x wave norm partials

  if (t < ZCHUNK) xs[t] = x[z0 + t];
  __syncthreads();              // only barrier with a full drain (prologue)
  const float th = thresh[0];

  const float4* __restrict__ W4 = reinterpret_cast<const float4*>(Wt) + t;

  float4 acc0 = {0,0,0,0}, acc1 = {0,0,0,0}, acc2 = {0,0,0,0}, acc3 = {0,0,0,0};

  // 4-deep register pipeline: named sets only (static indexing -> no scratch)
  float4 s0a,s0b,s0c,s0d, s1a,s1b,s1c,s1d, s2a,s2b,s2c,s2d, s3a,s3b,s3c,s3d;

#define LOADROW(S, r) do {                                                   \
    const float4* p_ = W4 + (size_t)(z0 + (r)) * NF4;                        \
    S##a = p_[0]; S##b = p_[256]; S##c = p_[512]; S##d = p_[768];            \
  } while (0)

#define FMA16(S, xz) do {                                                    \
    acc0.x = fmaf(xz, S##a.x, acc0.x); acc0.y = fmaf(xz, S##a.y, acc0.y);    \
    acc0.z = fmaf(xz, S##a.z, acc0.z); acc0.w = fmaf(xz, S##a.w, acc0.w);    \
    acc1.x = fmaf(xz, S##b.x, acc1.x); acc1.y = fmaf(xz, S##b.y, acc1.y);    \
    acc1.z = fmaf(xz, S##b.z, acc1.z); acc1.w = fmaf(xz, S##b.w, acc1.w);    \
    acc2.x = fmaf(xz, S##c.x, acc2.x); acc2.y = fmaf(xz, S##c.y, acc2.y);    \
    acc2.z = fmaf(xz, S##c.z, acc2.z); acc2.w = fmaf(xz, S##c.w, acc2.w);    \
    acc3.x = fmaf(xz, S##d.x, acc3.x); acc3.y = fmaf(xz, S##d.y, acc3.y);    \
    acc3.z = fmaf(xz, S##d.z, acc3.z); acc3.w = fmaf(xz, S##d.w, acc3.w);    \
  } while (0)

  // Row r body: squares(r) + wave-reduce(r) + red-write(r); the deferred
  // FMA(r-1) and the prefetch of row r+3 (into the just-freed PREV regs)
  // fill the shfl/barrier shadow; one raw barrier; then read norm(r) and
  // carry mask(r) to the next iteration.
#define ROW(CUR, PREV, r) do {                                               \
    float ss = CUR##a.x*CUR##a.x + CUR##a.y*CUR##a.y                         \
             + CUR##a.z*CUR##a.z + CUR##a.w*CUR##a.w                         \
             + CUR##b.x*CUR##b.x + CUR##b.y*CUR##b.y                         \
             + CUR##b.z*CUR##b.z + CUR##b.w*CUR##b.w                         \
             + CUR##c.x*CUR##c.x + CUR##c.y*CUR##c.y                         \
             + CUR##c.z*CUR##c.z + CUR##c.w*CUR##c.w                         \
             + CUR##d.x*CUR##d.x + CUR##d.y*CUR##d.y                         \
             + CUR##d.z*CUR##d.z + CUR##d.w*CUR##d.w;                        \
    ss += __shfl_xor(ss, 1, 64);                                             \
    ss += __shfl_xor(ss, 2, 64);                                             \
    ss += __shfl_xor(ss, 4, 64);                                             \
    ss += __shfl_xor(ss, 8, 64);                                             \
    ss += __shfl_xor(ss, 16, 64);                                            \
    ss += __shfl_xor(ss, 32, 64);                                            \
    if (lane == 0) red[(r) & 1][wv] = ss;                                    \
    if (mP) FMA16(PREV, xzP);          /* deferred FMA of row r-1 */         \
    if ((r) + 3 < ZCHUNK) LOADROW(PREV, (r) + 3); /* PREV regs now free */   \
    asm volatile("s_waitcnt lgkmcnt(0)" ::: "memory");                       \
    __builtin_amdgcn_s_barrier();                                            \
    asm volatile("" ::: "memory");                                           \
    const float n2 = red[(r) & 1][0] + red[(r) & 1][1]                       \
                   + red[(r) & 1][2] + red[(r) & 1][3];                      \
    const float xz = xs[(r)];                                                \
    mP  = (fabsf(xz) * sqrtf(n2) >= th);                                     \
    xzP = xz;                                                                \
  } while (0)

  LOADROW(s0, 0);
  LOADROW(s1, 1);
  LOADROW(s2, 2);

  float xzP = 0.0f;
  bool  mP  = false;

  for (int rb = 0; rb < 24; rb += 4) {
    ROW(s0, s3, rb + 0);
    ROW(s1, s0, rb + 1);
    ROW(s2, s1, rb + 2);
    ROW(s3, s2, rb + 3);
  }
  ROW(s0, s3, 24);
  ROW(s1, s0, 25);
  ROW(s2, s1, 26);
  ROW(s3, s2, 27);
  if (mP) FMA16(s3, xzP);   // epilogue: FMA of the last row

  // deterministic partial write (coalesced)
  float4* p4 = (float4*)part + (size_t)blockIdx.x * NF4;
  p4[t]       = acc0;
  p4[t + 256] = acc1;
  p4[t + 512] = acc2;
  p4[t + 768] = acc3;
#undef ROW
#undef FMA16
#undef LOADROW
}

// ---------------- reduce 512 partials -> y ----------------
// grid 256 blocks: block owns 4 float4 columns; thread (jg=t>>2, c=t&3)
// sums 8 partials, then two-stage LDS reduce 64 -> 8 -> 1.
__global__ __launch_bounds__(256) void reduce_parts(
    const float* __restrict__ part, float* __restrict__ y) {
  const int t  = threadIdx.x;
  const int c  = t & 3;
  const int jg = t >> 2;
  const int c4 = blockIdx.x * 4 + c;
  const float4* __restrict__ p4 = (const float4*)part;

  float4 s = {0.f, 0.f, 0.f, 0.f};
  #pragma unroll
  for (int jj = 0; jj < 8; ++jj) {
    const float4 v = p4[(size_t)(jg * 8 + jj) * NF4 + c4];
    s.x += v.x; s.y += v.y; s.z += v.z; s.w += v.w;
  }

  __shared__ float4 sh[64][4];
  sh[jg][c] = s;
  __syncthreads();
  if (jg < 8) {
    #pragma unroll
    for (int k = 1; k < 8; ++k) {
      const float4 v = sh[jg + 8 * k][c];
      s.x += v.x; s.y += v.y; s.z += v.z; s.w += v.w;
    }
    sh[jg][c] = s;
  }
  __syncthreads();
  if (jg == 0) {
    #pragma unroll
    for (int k = 1; k < 8; ++k) {
      const float4 v = sh[k][c];
      s.x += v.x; s.y += v.y; s.z += v.z; s.w += v.w;
    }
    ((float4*)y)[c4] = s;
  }
}

extern "C" void kernel_launch(void* const* d_in, const int* in_sizes, int n_in,
                              void* d_out, int out_size, void* d_ws, size_t ws_size,
                              hipStream_t stream) {
  const float* x      = (const float*)d_in[0];  // [1,1,Z]
  const float* Wt     = (const float*)d_in[1];  // [Z,N]
  const float* thresh = (const float*)d_in[2];  // [1]
  float* y            = (float*)d_out;          // [1,1,N]
  float* part         = (float*)d_ws;           // [NBLK][NDIM] = 8 MB

  fused_norm_gemv<<<NBLK, 256, 0, stream>>>(x, Wt, thresh, part);
  reduce_parts<<<NF4 / 4, 256, 0, stream>>>(part, y);
}

// Round 6
// 44.206 us; speedup vs baseline: 1.0451x; 1.0451x over previous
//
#include <hip/hip_runtime.h>
#include <cmath>

// Masked decode-GEMV: y[n] = sum_z m_z * x_z * W_t[z,n],
// m_z = (|x_z| * ||W_t[z,:]||_2 >= thresh).
//
// Single-read fused design, v3 (one barrier per row):
//   F: 4-deep LDS row ring via global_load_lds; per row ONE raw s_barrier
//      that simultaneously covers (a) staging-complete for this row
//      (counted vmcnt(8) before it), (b) visibility of the previous row's
//      cross-wave norm partials, (c) safety of restaging the slot read
//      last row (lgkmcnt(0) precedes every barrier). FMA of row r-1 runs
//      from carried registers in the shadow of row r's ds_reads.
//   C: reduce 512 partial vectors -> y.
// W is read from HBM exactly once (235 MB); no atomics anywhere.

#define ZDIM   14336
#define NDIM   4096
#define NF4    1024       // float4 per row
#define ZCHUNK 28         // rows per block
#define NBLK   512        // ZDIM / ZCHUNK -> exactly 2 blocks per CU
#define DEPTH  4          // LDS ring depth (64 KB)

typedef const __attribute__((address_space(1))) float* gas_fp;
typedef __attribute__((address_space(3))) float* las_fp;

__global__ __launch_bounds__(256, 2) void fused_norm_gemv(
    const float* __restrict__ x,
    const float* __restrict__ Wt,
    const float* __restrict__ thresh,
    float* __restrict__ part) {
  const int t    = threadIdx.x;
  const int lane = t & 63;
  const int wv   = t >> 6;
  const int z0   = blockIdx.x * ZCHUNK;

  __shared__ float ring[DEPTH][NDIM];   // 64 KB row ring
  __shared__ float xs[ZCHUNK];
  __shared__ float red[2][4];           // parity x wave norm partials

  if (t < ZCHUNK) xs[t] = x[z0 + t];
  const float th = thresh[0];
  __syncthreads();   // full drain BEFORE any staging is outstanding

  // staging layout linear per wave: wave wv covers floats [wv*1024, +1024)
  const int soff = wv * 1024 + lane * 4;

#define STAGE(slot, zrow) do {                                               \
    const float* gsrc = Wt + (size_t)(zrow) * NDIM + soff;                   \
    float* ldst = &ring[slot][soff];                                         \
    __builtin_amdgcn_global_load_lds((gas_fp)(gsrc      ), (las_fp)(ldst      ), 16, 0, 0); \
    __builtin_amdgcn_global_load_lds((gas_fp)(gsrc + 256), (las_fp)(ldst + 256), 16, 0, 0); \
    __builtin_amdgcn_global_load_lds((gas_fp)(gsrc + 512), (las_fp)(ldst + 512), 16, 0, 0); \
    __builtin_amdgcn_global_load_lds((gas_fp)(gsrc + 768), (las_fp)(ldst + 768), 16, 0, 0); \
  } while (0)

  STAGE(0, z0 + 0);
  STAGE(1, z0 + 1);
  STAGE(2, z0 + 2);    // 12 loads outstanding entering row 0

  float4 acc0 = {0,0,0,0}, acc1 = {0,0,0,0}, acc2 = {0,0,0,0}, acc3 = {0,0,0,0};
  // two alternating named row-register sets (static names -> no scratch)
  float4 Aa, Ab, Ac, Ad, Ba, Bb, Bc, Bd;

#define FMA16(S, xz) do {                                                    \
    acc0.x = fmaf(xz, S##a.x, acc0.x); acc0.y = fmaf(xz, S##a.y, acc0.y);    \
    acc0.z = fmaf(xz, S##a.z, acc0.z); acc0.w = fmaf(xz, S##a.w, acc0.w);    \
    acc1.x = fmaf(xz, S##b.x, acc1.x); acc1.y = fmaf(xz, S##b.y, acc1.y);    \
    acc1.z = fmaf(xz, S##b.z, acc1.z); acc1.w = fmaf(xz, S##b.w, acc1.w);    \
    acc2.x = fmaf(xz, S##c.x, acc2.x); acc2.y = fmaf(xz, S##c.y, acc2.y);    \
    acc2.z = fmaf(xz, S##c.z, acc2.z); acc2.w = fmaf(xz, S##c.w, acc2.w);    \
    acc3.x = fmaf(xz, S##d.x, acc3.x); acc3.y = fmaf(xz, S##d.y, acc3.y);    \
    acc3.z = fmaf(xz, S##d.z, acc3.z); acc3.w = fmaf(xz, S##d.w, acc3.w);    \
  } while (0)

  // Row r body (CUR receives row r; PRV holds row r-1 data):
  //   vmcnt(VM) -> barrier -> restage freed slot -> ds_read row r ->
  //   [deferred: n2(r-1), mask, FMA16(PRV)] -> squares+shfl(r) ->
  //   red write -> lgkm drain.
#define ROW(r, VM, CUR, PRV, DO_STAGE, DO_FMA) do {                          \
    asm volatile("s_waitcnt vmcnt(" #VM ")" ::: "memory");                   \
    __builtin_amdgcn_s_barrier();                                            \
    asm volatile("" ::: "memory");                                           \
    if (DO_STAGE) STAGE(((r) + 3) & (DEPTH - 1), z0 + (r) + 3);              \
    const float4* r4 = (const float4*)&ring[(r) & (DEPTH - 1)][0];           \
    CUR##a = r4[t]; CUR##b = r4[t + 256];                                    \
    CUR##c = r4[t + 512]; CUR##d = r4[t + 768];                              \
    if (DO_FMA) {                                                            \
      const int pp = ((r) + 1) & 1;                                          \
      const float n2 = red[pp][0] + red[pp][1] + red[pp][2] + red[pp][3];    \
      const float xz = xs[(r) - 1];                                          \
      if (fabsf(xz) * sqrtf(n2) >= th) FMA16(PRV, xz);                       \
    }                                                                        \
    float ss = CUR##a.x*CUR##a.x + CUR##a.y*CUR##a.y                         \
             + CUR##a.z*CUR##a.z + CUR##a.w*CUR##a.w                         \
             + CUR##b.x*CUR##b.x + CUR##b.y*CUR##b.y                         \
             + CUR##b.z*CUR##b.z + CUR##b.w*CUR##b.w                         \
             + CUR##c.x*CUR##c.x + CUR##c.y*CUR##c.y                         \
             + CUR##c.z*CUR##c.z + CUR##c.w*CUR##c.w                         \
             + CUR##d.x*CUR##d.x + CUR##d.y*CUR##d.y                         \
             + CUR##d.z*CUR##d.z + CUR##d.w*CUR##d.w;                        \
    ss += __shfl_xor(ss, 1, 64);                                             \
    ss += __shfl_xor(ss, 2, 64);                                             \
    ss += __shfl_xor(ss, 4, 64);                                             \
    ss += __shfl_xor(ss, 8, 64);                                             \
    ss += __shfl_xor(ss, 16, 64);                                            \
    ss += __shfl_xor(ss, 32, 64);                                            \
    if (lane == 0) red[(r) & 1][wv] = ss;                                    \
    asm volatile("s_waitcnt lgkmcnt(0)" ::: "memory");                       \
  } while (0)

  ROW(0, 8, A, B, 1, 0);
  for (int rb = 1; rb <= 23; rb += 2) {   // rows 1..24 (row 24 stages row 27)
    ROW(rb,     8, B, A, 1, 1);
    ROW(rb + 1, 8, A, B, 1, 1);
  }
  ROW(25, 8, B, A, 0, 1);
  ROW(26, 4, A, B, 0, 1);
  ROW(27, 0, B, A, 0, 1);

  // epilogue: norm of row 27 needs one more barrier for red visibility
  __builtin_amdgcn_s_barrier();
  asm volatile("" ::: "memory");
  {
    const float n2 = red[1][0] + red[1][1] + red[1][2] + red[1][3];
    const float xz = xs[27];
    if (fabsf(xz) * sqrtf(n2) >= th) FMA16(B, xz);
  }

  float4* p4 = (float4*)part + (size_t)blockIdx.x * NF4;
  p4[t]       = acc0;
  p4[t + 256] = acc1;
  p4[t + 512] = acc2;
  p4[t + 768] = acc3;
#undef ROW
#undef FMA16
#undef STAGE
}

// ---------------- reduce 512 partials -> y ----------------
__global__ __launch_bounds__(256) void reduce_parts(
    const float* __restrict__ part, float* __restrict__ y) {
  const int t  = threadIdx.x;
  const int c  = t & 3;
  const int jg = t >> 2;
  const int c4 = blockIdx.x * 4 + c;
  const float4* __restrict__ p4 = (const float4*)part;

  float4 s = {0.f, 0.f, 0.f, 0.f};
  #pragma unroll
  for (int jj = 0; jj < 8; ++jj) {
    const float4 v = p4[(size_t)(jg * 8 + jj) * NF4 + c4];
    s.x += v.x; s.y += v.y; s.z += v.z; s.w += v.w;
  }

  __shared__ float4 sh[64][4];
  sh[jg][c] = s;
  __syncthreads();
  if (jg < 8) {
    #pragma unroll
    for (int k = 1; k < 8; ++k) {
      const float4 v = sh[jg + 8 * k][c];
      s.x += v.x; s.y += v.y; s.z += v.z; s.w += v.w;
    }
    sh[jg][c] = s;
  }
  __syncthreads();
  if (jg == 0) {
    #pragma unroll
    for (int k = 1; k < 8; ++k) {
      const float4 v = sh[k][c];
      s.x += v.x; s.y += v.y; s.z += v.z; s.w += v.w;
    }
    ((float4*)y)[c4] = s;
  }
}

extern "C" void kernel_launch(void* const* d_in, const int* in_sizes, int n_in,
                              void* d_out, int out_size, void* d_ws, size_t ws_size,
                              hipStream_t stream) {
  const float* x      = (const float*)d_in[0];  // [1,1,Z]
  const float* Wt     = (const float*)d_in[1];  // [Z,N]
  const float* thresh = (const float*)d_in[2];  // [1]
  float* y            = (float*)d_out;          // [1,1,N]
  float* part         = (float*)d_ws;           // [NBLK][NDIM] = 8 MB

  fused_norm_gemv<<<NBLK, 256, 0, stream>>>(x, Wt, thresh, part);
  reduce_parts<<<NF4 / 4, 256, 0, stream>>>(part, y);
}